// Round 15
// baseline (232.119 us; speedup 1.0000x reference)
//
#include <hip/hip_runtime.h>
#include <hip/hip_bf16.h>
#include <math.h>

#define NN 50000
#define EE 800000
#define DIN 128
#define HEADS 8
#define DH 16
#define DOUT 16
#define NEG 0.2f
#define GM 32       // nodes per GEMM block
#define GB ((NN + GM - 1) / GM)     // 1563 gemm blocks
#define NB ((NN + 255) / 256)       // 196 init blocks
#define DEGB ((EE / 4 + 255) / 256) // 782 edge-quad blocks
#define PAD 64      // padded CSR row; 2 shards x 32 slots (shard0 incl. self-loop)

typedef __attribute__((ext_vector_type(8))) short bf16x8;
typedef __attribute__((ext_vector_type(4))) float f32x4;

__device__ __forceinline__ unsigned pack2bf(float a, float b) {
    union { __hip_bfloat162 h; unsigned u; } c;
    c.h = __float22bfloat162_rn(make_float2(a, b));
    return c.u;
}
__device__ __forceinline__ unsigned short f2bf(float v) {
    union { __hip_bfloat16 h; unsigned short u; } c;
    c.h = __float2bfloat16(v);
    return c.u;
}
__device__ __forceinline__ float bflo(unsigned u) { return __uint_as_float(u << 16); }
__device__ __forceinline__ float bfhi(unsigned u) { return __uint_as_float(u & 0xffff0000u); }

// ---------- init: cnt0=1/cnt1=0 + self-loop (0..NB) || Wb1 cvt || Wb2 cvt ----------
__global__ __launch_bounds__(256) void init_wcvt(int* __restrict__ cnt0,
                                                 int* __restrict__ cnt1,
                                                 int* __restrict__ esrcPad,
                                                 const float* __restrict__ Wl,
                                                 const float* __restrict__ Wr,
                                                 unsigned short* __restrict__ Wb,
                                                 const float* __restrict__ Wl2,
                                                 const float* __restrict__ Wr2,
                                                 unsigned short* __restrict__ Wb2) {
    int b = blockIdx.x, t = threadIdx.x;
    if (b < NB) {
        int i = b * 256 + t;
        if (i < NN) {
            cnt0[i] = 1;                   // slot 0 = self-loop (shard 0)
            cnt1[i] = 0;
            esrcPad[(size_t)i * PAD] = i;
        }
    } else if (b < NB + 128) {
        int i = (b - NB) * 256 + t;   // 32768 entries
        int n = i >> 7, k = i & 127;
        float v = (n < 128) ? Wl[k * 128 + n] : Wr[k * 128 + (n - 128)];
        Wb[i] = f2bf(v);
    } else {
        int i = (b - NB - 128) * 256 + t;  // 4096 entries: Wb2[n][k], n in [0,32)
        int n = i >> 7, k = i & 127;
        float v = (n < 16) ? Wl2[k * 16 + n] : Wr2[k * 16 + (n - 16)];
        Wb2[i] = f2bf(v);
    }
}

// ---------- fused: 2-way sharded padded fill (0..DEGB) || gemm1 MFMA (DEGB..) ----------
// shard = quad parity: shard0 -> slots [rowbase, rowbase+32), shard1 -> [rowbase+32, +64).
// One atomic per edge; contention 16 -> ~8 waiters/address (round-12/13 delta: ~16 us).
__global__ __launch_bounds__(256) void fill_gemm1(const int* __restrict__ ei,
                                                  int* __restrict__ cnt0,
                                                  int* __restrict__ cnt1,
                                                  int* __restrict__ esrcPad,
                                                  const float* __restrict__ x,
                                                  const unsigned short* __restrict__ Wb,
                                                  unsigned short* __restrict__ xlb,
                                                  float* __restrict__ xr) {
    __shared__ unsigned short As[GM][136];   // gemm1 path only; pad 128->136
    int t = threadIdx.x;
    if (blockIdx.x < DEGB) {   // ---- fill path ----
        int i = blockIdx.x * 256 + t;
        if (i >= EE / 4) return;
        int4 ss = ((const int4*)ei)[i];
        int4 dd = ((const int4*)(ei + EE))[i];
        int* __restrict__ cs = (i & 1) ? cnt1 : cnt0;
        int sbase = (i & 1) ? 32 : 0;    // shard1 slots start at +32 (p from 0); shard0 p starts at 1
        int p;
        p = atomicAdd(&cs[dd.x], 1); esrcPad[(size_t)dd.x * PAD + sbase + p] = ss.x;
        p = atomicAdd(&cs[dd.y], 1); esrcPad[(size_t)dd.y * PAD + sbase + p] = ss.y;
        p = atomicAdd(&cs[dd.z], 1); esrcPad[(size_t)dd.z * PAD + sbase + p] = ss.z;
        p = atomicAdd(&cs[dd.w], 1); esrcPad[(size_t)dd.w * PAD + sbase + p] = ss.w;
        return;
    }
    // ---- gemm1 path: 32 nodes x 256 cols, 4 waves; m89-verified 16x16x32 bf16 layouts ----
    int n0 = (blockIdx.x - DEGB) * GM;
    {   // stage: 32 rows x 128 ch fp32 -> bf16 LDS
        int row = t >> 3, seg = t & 7;
        int nsrc = n0 + row < NN ? n0 + row : NN - 1;   // clamp: safe read, store guarded
        const float4* xp = (const float4*)(x + (size_t)nsrc * DIN + 16 * seg);
        float4 v0 = xp[0], v1 = xp[1], v2 = xp[2], v3 = xp[3];
        uint4 p0 = make_uint4(pack2bf(v0.x, v0.y), pack2bf(v0.z, v0.w),
                              pack2bf(v1.x, v1.y), pack2bf(v1.z, v1.w));
        uint4 p1 = make_uint4(pack2bf(v2.x, v2.y), pack2bf(v2.z, v2.w),
                              pack2bf(v3.x, v3.y), pack2bf(v3.z, v3.w));
        *(uint4*)&As[row][16 * seg]     = p0;
        *(uint4*)&As[row][16 * seg + 8] = p1;
    }
    __syncthreads();
    int lane = t & 63, w = t >> 6;
    int m = lane & 15, quad = lane >> 4;
    f32x4 acc[2][4];
#pragma unroll
    for (int mt = 0; mt < 2; ++mt)
#pragma unroll
        for (int nt = 0; nt < 4; ++nt) acc[mt][nt] = (f32x4){0.f, 0.f, 0.f, 0.f};
#pragma unroll
    for (int ks = 0; ks < 4; ++ks) {
        int k = 32 * ks + 8 * quad;
        bf16x8 a0 = *(const bf16x8*)&As[m][k];
        bf16x8 a1 = *(const bf16x8*)&As[16 + m][k];
#pragma unroll
        for (int nt = 0; nt < 4; ++nt) {
            int n = 64 * w + 16 * nt + m;
            bf16x8 b = *(const bf16x8*)(Wb + (size_t)n * 128 + k);
            acc[0][nt] = __builtin_amdgcn_mfma_f32_16x16x32_bf16(a0, b, acc[0][nt], 0, 0, 0);
            acc[1][nt] = __builtin_amdgcn_mfma_f32_16x16x32_bf16(a1, b, acc[1][nt], 0, 0, 0);
        }
    }
#pragma unroll
    for (int mt = 0; mt < 2; ++mt) {
#pragma unroll
        for (int nt = 0; nt < 4; ++nt) {
            int col = 64 * w + 16 * nt + m;       // wave-uniform half selection
            int rbase = n0 + 16 * mt + 4 * quad;
            if (col < 128) {
#pragma unroll
                for (int r = 0; r < 4; ++r) {
                    int row = rbase + r;
                    if (row < NN) xlb[(size_t)row * DIN + col] = f2bf(acc[mt][nt][r]);
                }
            } else {
#pragma unroll
                for (int r = 0; r < 4; ++r) {
                    int row = rbase + r;
                    if (row < NN) xr[(size_t)row * DIN + (col - 128)] = acc[mt][nt][r];
                }
            }
        }
    }
}

// ---------- layer-1 fused: logits + segment softmax + gather + bias + ELU -> bf16 hb ----------
// one wave per dst; quarter-wave per virtual slot: 16 lanes x 8 bf16 channels.
// Virtual index v in [0, t0+c1): phys = v + (v < t0 ? rs : rs+32-t0).
__global__ __launch_bounds__(256) void l1_fused(const int* __restrict__ esrcPad,
                                                const int* __restrict__ cnt0,
                                                const int* __restrict__ cnt1,
                                                const unsigned short* __restrict__ xlb,
                                                const float* __restrict__ xr,
                                                const float* __restrict__ att,
                                                const float* __restrict__ bias,
                                                unsigned short* __restrict__ hb) {
    int d = blockIdx.x * 4 + (threadIdx.x >> 6);    // NN % 4 == 0
    int lane = threadIdx.x & 63;
    int quarter = lane >> 4;
    int q16 = lane & 15;        // channel octet [8*q16, 8*q16+8)
    int rs = d * PAD;
    int t0 = cnt0[d];           // includes self-loop; >= 1
    int total = t0 + cnt1[d];
    int off1 = rs + 32 - t0;    // shard-1 remap
    int last = total - 1;
    float4 xr0 = ((const float4*)(xr + (size_t)d * DIN))[2 * q16];
    float4 xr1 = ((const float4*)(xr + (size_t)d * DIN))[2 * q16 + 1];
    float4 at0 = ((const float4*)att)[2 * q16];
    float4 at1 = ((const float4*)att)[2 * q16 + 1];
    float4 a0 = make_float4(0.f, 0.f, 0.f, 0.f);
    float4 a1 = make_float4(0.f, 0.f, 0.f, 0.f);
    float l = 0.f;
    int v = quarter;
    int c0 = v < last ? v : last;
    int s0 = esrcPad[c0 + (c0 < t0 ? rs : off1)];
    int c1 = v + 4 < last ? v + 4 : last;
    int s1 = esrcPad[c1 + (c1 < t0 ? rs : off1)];
    uint4 row = ((const uint4*)(xlb + (size_t)s0 * DIN))[q16];
    for (; v < total; v += 4) {
        uint4 cur = row;
        int c2 = v + 8 < last ? v + 8 : last;
        int s2 = esrcPad[c2 + (c2 < t0 ? rs : off1)];         // 2 ahead
        row = ((const uint4*)(xlb + (size_t)s1 * DIN))[q16];  // 1 ahead
        s1 = s2;
        float f0 = bflo(cur.x), f1 = bfhi(cur.x);
        float f2 = bflo(cur.y), f3 = bfhi(cur.y);
        float f4 = bflo(cur.z), f5 = bfhi(cur.z);
        float f6 = bflo(cur.w), f7 = bfhi(cur.w);
        float v0 = f0 + xr0.x; v0 = fmaxf(v0, NEG * v0);
        float v1 = f1 + xr0.y; v1 = fmaxf(v1, NEG * v1);
        float v2 = f2 + xr0.z; v2 = fmaxf(v2, NEG * v2);
        float v3 = f3 + xr0.w; v3 = fmaxf(v3, NEG * v3);
        float v4 = f4 + xr1.x; v4 = fmaxf(v4, NEG * v4);
        float v5 = f5 + xr1.y; v5 = fmaxf(v5, NEG * v5);
        float v6 = f6 + xr1.z; v6 = fmaxf(v6, NEG * v6);
        float v7 = f7 + xr1.w; v7 = fmaxf(v7, NEG * v7);
        float w = at0.x * v0 + at0.y * v1 + at0.z * v2 + at0.w * v3
                + at1.x * v4 + at1.y * v5 + at1.z * v6 + at1.w * v7;
        w += __shfl_xor(w, 1);          // full 16-ch head logit (lane pair)
        float p = __expf(w);
        a0.x += p * f0; a0.y += p * f1; a0.z += p * f2; a0.w += p * f3;
        a1.x += p * f4; a1.y += p * f5; a1.z += p * f6; a1.w += p * f7;
        l += p;
    }
#pragma unroll
    for (int off = 16; off < 64; off <<= 1) {
        a0.x += __shfl_xor(a0.x, off); a0.y += __shfl_xor(a0.y, off);
        a0.z += __shfl_xor(a0.z, off); a0.w += __shfl_xor(a0.w, off);
        a1.x += __shfl_xor(a1.x, off); a1.y += __shfl_xor(a1.y, off);
        a1.z += __shfl_xor(a1.z, off); a1.w += __shfl_xor(a1.w, off);
        l += __shfl_xor(l, off);
    }
    if (quarter == 0) {
        float inv = 1.f / l;
        float4 b0 = ((const float4*)bias)[2 * q16];
        float4 b1 = ((const float4*)bias)[2 * q16 + 1];
        float4 o0, o1;
        o0.x = a0.x * inv + b0.x; o0.x = o0.x > 0.f ? o0.x : expm1f(o0.x);
        o0.y = a0.y * inv + b0.y; o0.y = o0.y > 0.f ? o0.y : expm1f(o0.y);
        o0.z = a0.z * inv + b0.z; o0.z = o0.z > 0.f ? o0.z : expm1f(o0.z);
        o0.w = a0.w * inv + b0.w; o0.w = o0.w > 0.f ? o0.w : expm1f(o0.w);
        o1.x = a1.x * inv + b1.x; o1.x = o1.x > 0.f ? o1.x : expm1f(o1.x);
        o1.y = a1.y * inv + b1.y; o1.y = o1.y > 0.f ? o1.y : expm1f(o1.y);
        o1.z = a1.z * inv + b1.z; o1.z = o1.z > 0.f ? o1.z : expm1f(o1.z);
        o1.w = a1.w * inv + b1.w; o1.w = o1.w > 0.f ? o1.w : expm1f(o1.w);
        uint4 pk = make_uint4(pack2bf(o0.x, o0.y), pack2bf(o0.z, o0.w),
                              pack2bf(o1.x, o1.y), pack2bf(o1.z, o1.w));
        ((uint4*)(hb + (size_t)d * DIN))[q16] = pk;
    }
}

// ---------- layer-2 GEMM via MFMA: [xl2 | xr2] = hb @ [Wl2 | Wr2] ----------
__global__ __launch_bounds__(256) void gemm2(const unsigned short* __restrict__ hb,
                                             const unsigned short* __restrict__ Wb2,
                                             float* __restrict__ xl2, float* __restrict__ xr2) {
    __shared__ unsigned short As[GM][136];
    int t = threadIdx.x;
    int n0 = blockIdx.x * GM;
    {   // stage 32 bf16 rows (256B each): 8 threads/row x 2 uint4
        int row = t >> 3, s8 = t & 7;
        int nsrc = n0 + row < NN ? n0 + row : NN - 1;
        const uint4* src = (const uint4*)(hb + (size_t)nsrc * DIN);
        *(uint4*)&As[row][8 * s8]      = src[s8];
        *(uint4*)&As[row][8 * s8 + 64] = src[s8 + 8];
    }
    __syncthreads();
    int lane = t & 63, w = t >> 6;
    int m = lane & 15, quad = lane >> 4;
    int mt = w & 1, nt = w >> 1;
    f32x4 acc = (f32x4){0.f, 0.f, 0.f, 0.f};
#pragma unroll
    for (int ks = 0; ks < 4; ++ks) {
        int k = 32 * ks + 8 * quad;
        bf16x8 a = *(const bf16x8*)&As[16 * mt + m][k];
        bf16x8 b = *(const bf16x8*)(Wb2 + (size_t)(16 * nt + m) * 128 + k);
        acc = __builtin_amdgcn_mfma_f32_16x16x32_bf16(a, b, acc, 0, 0, 0);
    }
    float* __restrict__ dst = (nt == 0) ? xl2 : xr2;
#pragma unroll
    for (int r = 0; r < 4; ++r) {
        int node = n0 + 16 * mt + 4 * quad + r;
        if (node < NN) dst[(size_t)node * DOUT + m] = acc[r];
    }
}

// ---------- layer-2 fused: softmax + gather + bias + log_softmax ----------
__global__ __launch_bounds__(256) void l2_fused(const int* __restrict__ esrcPad,
                                                const int* __restrict__ cnt0,
                                                const int* __restrict__ cnt1,
                                                const float* __restrict__ xl,
                                                const float* __restrict__ xr,
                                                const float* __restrict__ att,
                                                const float* __restrict__ bias,
                                                float* __restrict__ out) {
    int d = blockIdx.x * 4 + (threadIdx.x >> 6);    // NN % 4 == 0
    int lane = threadIdx.x & 63;
    int sl = lane >> 2;     // virtual slot group 0..15
    int q = lane & 3;       // channel quad
    int rs = d * PAD;
    int t0 = cnt0[d];
    int total = t0 + cnt1[d];
    int off1 = rs + 32 - t0;
    int last = total - 1;
    float4 xrq = ((const float4*)(xr + (size_t)d * DOUT))[q];
    float4 atq = ((const float4*)att)[q];
    float4 acc = make_float4(0.f, 0.f, 0.f, 0.f);
    float l = 0.f;
    int v = sl;
    int c0 = v < last ? v : last;
    int s0 = esrcPad[c0 + (c0 < t0 ? rs : off1)];
    for (; v < total; v += 16) {
        int c1 = v + 16 < last ? v + 16 : last;
        int s1 = esrcPad[c1 + (c1 < t0 ? rs : off1)];
        float4 cur = ((const float4*)(xl + (size_t)s0 * DOUT))[q];
        s0 = s1;
        float v0 = cur.x + xrq.x; v0 = fmaxf(v0, NEG * v0);
        float v1 = cur.y + xrq.y; v1 = fmaxf(v1, NEG * v1);
        float v2 = cur.z + xrq.z; v2 = fmaxf(v2, NEG * v2);
        float v3 = cur.w + xrq.w; v3 = fmaxf(v3, NEG * v3);
        float w = atq.x * v0 + atq.y * v1 + atq.z * v2 + atq.w * v3;
        w += __shfl_xor(w, 1);
        w += __shfl_xor(w, 2);          // full 16-ch logit
        float p = __expf(w);
        acc.x += p * cur.x; acc.y += p * cur.y;
        acc.z += p * cur.z; acc.w += p * cur.w;
        l += p;
    }
#pragma unroll
    for (int off = 4; off < 64; off <<= 1) {
        acc.x += __shfl_xor(acc.x, off);
        acc.y += __shfl_xor(acc.y, off);
        acc.z += __shfl_xor(acc.z, off);
        acc.w += __shfl_xor(acc.w, off);
        l += __shfl_xor(l, off);
    }
    float inv = 1.f / l;
    float4 b = ((const float4*)bias)[q];
    float4 vv;
    vv.x = acc.x * inv + b.x; vv.y = acc.y * inv + b.y;
    vv.z = acc.z * inv + b.z; vv.w = acc.w * inv + b.w;
    float m = fmaxf(fmaxf(vv.x, vv.y), fmaxf(vv.z, vv.w));
    m = fmaxf(m, __shfl_xor(m, 1));
    m = fmaxf(m, __shfl_xor(m, 2));
    float es = __expf(vv.x - m) + __expf(vv.y - m) + __expf(vv.z - m) + __expf(vv.w - m);
    es += __shfl_xor(es, 1);
    es += __shfl_xor(es, 2);
    float lse = m + __logf(es);
    if (sl == 0) {
        ((float4*)(out + (size_t)d * DOUT))[q] = vv;
        float4 ls;
        ls.x = vv.x - lse; ls.y = vv.y - lse; ls.z = vv.z - lse; ls.w = vv.w - lse;
        ((float4*)(out + (size_t)NN * DOUT + (size_t)d * DOUT))[q] = ls;
    }
}

extern "C" void kernel_launch(void* const* d_in, const int* in_sizes, int n_in,
                              void* d_out, int out_size, void* d_ws, size_t ws_size,
                              hipStream_t stream) {
    const float* x     = (const float*)d_in[0];
    const int*   ei    = (const int*)d_in[1];
    const float* Wl1   = (const float*)d_in[2];
    const float* Wr1   = (const float*)d_in[3];
    const float* att1  = (const float*)d_in[4];
    const float* bias1 = (const float*)d_in[5];
    const float* Wl2   = (const float*)d_in[6];
    const float* Wr2   = (const float*)d_in[7];
    const float* att2  = (const float*)d_in[8];
    const float* bias2 = (const float*)d_in[9];
    float* out = (float*)d_out;

    // ---- workspace layout ----
    float* xr1    = (float*)d_ws;                    // NN*128 fp32
    float* xl2    = xr1 + (size_t)NN * DIN;          // NN*16
    float* xr2    = xl2 + (size_t)NN * DOUT;         // NN*16
    unsigned short* xlb = (unsigned short*)(xr2 + (size_t)NN * DOUT); // NN*128 bf16
    unsigned short* hb  = xlb + (size_t)NN * DIN;    // NN*128 bf16
    unsigned short* Wb  = hb + (size_t)NN * DIN;     // 256*128 bf16
    unsigned short* Wb2 = Wb + 256 * 128;            // 32*128 bf16
    int*   esrcPad = (int*)(Wb2 + 32 * 128);         // NN*64 padded CSR (2 shards x 32)
    int*   cnt0   = esrcPad + (size_t)NN * PAD;      // NN
    int*   cnt1   = cnt0 + NN;                       // NN

    const int B = 256;
    init_wcvt<<<NB + 144, B, 0, stream>>>(cnt0, cnt1, esrcPad, Wl1, Wr1, Wb, Wl2, Wr2, Wb2);
    fill_gemm1<<<DEGB + GB, B, 0, stream>>>(ei, cnt0, cnt1, esrcPad, x, Wb, xlb, xr1);

    l1_fused<<<NN / 4, B, 0, stream>>>(esrcPad, cnt0, cnt1, xlb, xr1, att1, bias1, hb);

    gemm2<<<GB, B, 0, stream>>>(hb, Wb2, xl2, xr2);

    l2_fused<<<NN / 4, B, 0, stream>>>(esrcPad, cnt0, cnt1, xl2, xr2, att2, bias2, out);
}